// Round 7
// baseline (184.969 us; speedup 1.0000x reference)
//
#include <hip/hip_runtime.h>
#include <hip/hip_bf16.h>

// Problem constants (from reference setup_inputs)
constexpr int K    = 64;
constexpr int N    = 1024;
constexpr int DIN  = 16;
constexpr int H1   = 4;
constexpr int DOUT = 8;
constexpr int FC1  = 54;

#define ALPHA_F   (0.01f)
#define LOG2E_F   (1.4426950408889634f)

typedef unsigned int uint;
typedef unsigned long long ull;
typedef short  bf16x8 __attribute__((ext_vector_type(8)));
typedef float  f32x4  __attribute__((ext_vector_type(4)));

__device__ inline float fast_exp2(float x) {
#if __has_builtin(__builtin_amdgcn_exp2f)
    return __builtin_amdgcn_exp2f(x);      // raw v_exp_f32
#else
    return __expf(x * 0.6931471805599453f);
#endif
}

// packed bf16 pair (RNE) -> uint (lo=a, hi=b); v_cvt_pk_bf16_f32 on gfx950
__device__ inline uint pk_bf16(float a, float b) {
    union { __hip_bfloat162 h; uint u; } v;
    v.h = __float22bfloat162_rn(make_float2(a, b));
    return v.u;
}

// Device-scope (agent) relaxed stores: compile to global_store ... sc1 —
// write-through to the device coherence point.  Consumers read these lines
// with NORMAL cached loads: every handed-off line is first-touched by its
// consumer AFTER the group barrier (kernel-entry acquire invalidated all
// caches; nobody reads these addresses before the producer writes them),
// so no stale copy can exist and no buffer_inv is ever needed.
__device__ __forceinline__ void store_dev(float* p, float v) {
    __hip_atomic_store(p, v, __ATOMIC_RELAXED, __HIP_MEMORY_SCOPE_AGENT);
}
__device__ __forceinline__ void store_dev64(ull* p, ull v) {
    __hip_atomic_store(p, v, __ATOMIC_RELAXED, __HIP_MEMORY_SCOPE_AGENT);
}

// ---------------------------------------------------------------------------
// Per-k GROUP barrier (8 blocks: 8k..8k+7).  R6 lesson: grid barriers cost
// ~20us each (global skew + 512x wbl2/inv refetch storms).  Groups are
// independent -> skew stays local, groups pipeline.  No fences: data handoff
// is via sc1 stores (above); __syncthreads' vmcnt(0) drain before s_barrier
// guarantees all waves' stores are at the coherence point before thread 0
// announces arrival.  Ticket epochs of 8 -> self-consistent across graph
// replays with zero-init __device__ counters (never in poisoned ws).
// Deadlock-safe: grid 512 = 2 blocks/CU x 256 CU all co-resident
// (__launch_bounds__(512,4) caps VGPR at 128; LDS 34.5 KB).
// ---------------------------------------------------------------------------
__device__ ull g_grp[3][64][16];            // [barrier][k][pad 128B]

__device__ __forceinline__ void group_barrier(int b, int k, bool wait) {
    __syncthreads();   // all waves' stores drained (vmcnt0 before s_barrier)
    if (threadIdx.x == 0) {
        ull t = __hip_atomic_fetch_add(&g_grp[b][k][0], 1ull,
                    __ATOMIC_RELAXED, __HIP_MEMORY_SCOPE_AGENT);
        if (wait) {
            const ull tgt = ((t >> 3) << 3) + 8ull;     // this epoch's target
            while (__hip_atomic_load(&g_grp[b][k][0],
                       __ATOMIC_RELAXED, __HIP_MEMORY_SCOPE_SYSTEM) < tgt) {
                __builtin_amdgcn_s_sleep(1);
            }
        }
    }
    __syncthreads();
}

// ---------------------------------------------------------------------------
// B-fragment table layout (consumed by mfma_f32_16x16x32_bf16):
//   HB[k][c][lane] : uint4;  lane=(q=lane>>4, n=lane&15)
//   dword t packs rows j=c*32+q*8+2t, +2t+1 of column n:
//   n<F -> bf16(h[j][n]); n==F -> 1.0 (denominator column); n>F -> 0.
// ---------------------------------------------------------------------------

struct SharedBufs {
    ull   mask[128 * 18];  // 18 KB: this block's 128 query rows x 16 jw words,
                           // row stride 18 u64 (144B) -> 2-way bank alias only
    float F2s[1024];       // f2[k] (4 KB)
    float XPa[8][16][5];   // FUSE: attn output xo
    float XPb[8][16][9];   // FUSE: projected hv / !FUSE: xo tile
    float YPs[8][64];      // !FUSE: per-wave fc1 partials
    float hrow[128 * 4];   // P0 proj row-stage
    float f1s[128];        // f1 logits of this block's rows (never global!)
    float ybuf[FC1];       // P3 fc1 activations
};  // ~34.5 KB; 2 blocks/CU -> 69 KB/CU, far under 160 KB

// ---------------------------------------------------------------------------
// Attention phase (main loop instruction-identical to R2/R6 except the mask
// source is now block-local LDS).  FUSE (layer 1): epilogue computes layer-2
// projection, writes HB2 frags (sc1) + f22 (sc1) + f1s (LDS).
// !FUSE (layer 2): epilogue computes per-wave fc1 partials; block-reduces;
// writes race-free slot yp[(k*8+s)*64+c] (sc1).
// ---------------------------------------------------------------------------
template <int F, bool FUSE>
__device__ __forceinline__ void attn_phase(
        const uint4* __restrict__ HBin,  // [K][32][64] B-frags
        const float* __restrict__ f2,    // [K,N] logits (x log2e), group-made
        const float* __restrict__ W2,    // [4,8]  (FUSE only)
        const float* __restrict__ a2,    // [16]   (FUSE only)
        const float* __restrict__ fc1w,  // [8192,54] (!FUSE only)
        uint4* __restrict__ HBout,       // FUSE: HB2 table
        float* __restrict__ yp,          // !FUSE: fc1 partial slots [512][64]
        float* __restrict__ o_f2,        // FUSE: f22 (x log2e)
        SharedBufs& S, int k, int s) {
    const int tid  = threadIdx.x;
    const int lane = tid & 63;
    const int wv   = tid >> 6;
    const int quad = lane >> 4;
    const int n16  = lane & 15;

    if (tid < 256)
        ((float4*)S.F2s)[tid] = ((const float4*)(f2 + k * N))[tid];
    __syncthreads();

    const int itile = s * 8 + wv;                    // 0..63
    const int ibase = itile * 16;
    const float f1v = S.f1s[wv * 16 + n16];          // own-row logit (LDS)
    const uint4* mrow = (const uint4*)&S.mask[(wv * 16 + n16) * 18];
    const uint4* HBk  = HBin + (size_t)k * 2048;

    f32x4 acc = {0.f, 0.f, 0.f, 0.f};
    union { bf16x8 v; uint u[4]; } af;
    union { bf16x8 v; uint4 q; }  bfrag;

    #pragma unroll 2
    for (int g = 0; g < 8; g++) {
        const uint4 Mg = mrow[g];                    // 4 chunks of mask bits (LDS)
        #pragma unroll
        for (int cc = 0; cc < 4; cc++) {
            const int c = g * 4 + cc;
            const uint mdw = (cc == 0) ? Mg.x : (cc == 1) ? Mg.y
                           : (cc == 2) ? Mg.z : Mg.w;
            const uint mb  = (mdw >> (quad * 8)) & 0xffu;  // 8 bits, this lane
            float4 fa = *(const float4*)(S.F2s + c * 32 + quad * 8);
            float4 fb = *(const float4*)(S.F2s + c * 32 + quad * 8 + 4);
            bfrag.q = HBk[c * 64 + lane];            // coalesced VMEM (L2/LLC)
            float f2e[8] = {fa.x, fa.y, fa.z, fa.w, fb.x, fb.y, fb.z, fb.w};
            float pv[8];
            #pragma unroll
            for (int jj = 0; jj < 8; jj++) {
                float x = f1v + f2e[jj];
                float e = fmaxf(x, ALPHA_F * x);     // leaky (log2-scaled)
                float p = fast_exp2(e);
                pv[jj] = (mb & (1u << jj)) ? p : 0.f;  // mask -> exact 0
            }
            #pragma unroll
            for (int pr = 0; pr < 4; pr++)
                af.u[pr] = pk_bf16(pv[2 * pr], pv[2 * pr + 1]);
            acc = __builtin_amdgcn_mfma_f32_16x16x32_bf16(af.v, bfrag.v, acc, 0, 0, 0);
        }
    }

    // ---- epilogue: C[m][n]: n=lane&15, m=quad*4+reg; denom in col n==F ----
    #pragma unroll
    for (int r = 0; r < 4; r++) {
        float den = __shfl(acc[r], (lane & 48) + F);
        float inv = (den > 0.f) ? 1.f / den : 0.f;
        float xo  = fmaxf(acc[r] * inv, 0.f);        // relu
        int m = quad * 4 + r;
        if constexpr (FUSE) {
            if (n16 < F) S.XPa[wv][m][n16] = xo;
        } else {
            if (n16 < F) S.XPb[wv][m][n16] = xo;     // wave-local stage
        }
    }

    if constexpr (FUSE) {
        __syncthreads();
        if (lane < 16) {
            const int m = lane;
            float x0 = S.XPa[wv][m][0], x1 = S.XPa[wv][m][1];
            float x2v = S.XPa[wv][m][2], x3 = S.XPa[wv][m][3];
            float hv[DOUT];
            #pragma unroll
            for (int f = 0; f < DOUT; f++) {
                hv[f] = x0 * W2[f]      + x1 * W2[8 + f]
                      + x2v * W2[16 + f] + x3 * W2[24 + f];
            }
            float t1 = 0.f, t2 = 0.f;
            #pragma unroll
            for (int f = 0; f < DOUT; f++) { t1 += hv[f] * a2[f]; t2 += hv[f] * a2[DOUT + f]; }
            S.f1s[wv * 16 + m] = t1 * LOG2E_F;       // own-row: LDS only
            store_dev(&o_f2[k * N + ibase + m], t2 * LOG2E_F);  // group-wide
            #pragma unroll
            for (int f = 0; f < DOUT; f++) S.XPb[wv][m][f] = hv[f];
        }
        __syncthreads();
        if (lane < 32) {
            const int c2    = ibase >> 5;
            const int qhalf = (ibase >> 4) & 1;
            const int ql    = lane >> 4;
            const int n     = lane & 15;
            const int q     = qhalf * 2 + ql;
            uint4 dw;
            if (n < DOUT) {
                dw.x = pk_bf16(S.XPb[wv][ql * 8 + 0][n], S.XPb[wv][ql * 8 + 1][n]);
                dw.y = pk_bf16(S.XPb[wv][ql * 8 + 2][n], S.XPb[wv][ql * 8 + 3][n]);
                dw.z = pk_bf16(S.XPb[wv][ql * 8 + 4][n], S.XPb[wv][ql * 8 + 5][n]);
                dw.w = pk_bf16(S.XPb[wv][ql * 8 + 6][n], S.XPb[wv][ql * 8 + 7][n]);
            } else if (n == DOUT) {
                dw = make_uint4(0x3f803f80u, 0x3f803f80u, 0x3f803f80u, 0x3f803f80u);
            } else {
                dw = make_uint4(0u, 0u, 0u, 0u);
            }
            ull* p = (ull*)&HBout[(size_t)k * 2048 + c2 * 64 + q * 16 + n];
            store_dev64(p,     (ull)dw.x | ((ull)dw.y << 32));
            store_dev64(p + 1, (ull)dw.z | ((ull)dw.w << 32));
        }
    } else {
        // ---- fused fc1: per-wave partial over this wave's 128 x2-columns ----
        const int ceff = (lane < FC1) ? lane : 0;    // c = lane (54 active)
        const float* wb = fc1w + (size_t)ibase * DOUT * FC1;
        float pacc = 0.f;
        #pragma unroll 8
        for (int mm = 0; mm < 128; mm++) {
            float xv = S.XPb[wv][mm >> 3][mm & 7];   // wave-uniform broadcast
            pacc = fmaf(xv, wb[(size_t)mm * FC1 + ceff], pacc);
        }
        S.YPs[wv][lane] = pacc;
        __syncthreads();
        if (tid < 64) {
            float sum = 0.f;
            #pragma unroll
            for (int w = 0; w < 8; w++) sum += S.YPs[w][tid];
            store_dev(&yp[(k * 8 + s) * 64 + tid], sum);   // race-free slot
        }
    }
}

// ---------------------------------------------------------------------------
// Mega kernel v3: ZERO grid-wide syncs.  512 blocks x 512 threads; block
// (k=bid>>3, s=bid&7) owns query rows [s*128, s*128+128) of graph k for the
// whole pipeline.  3 per-k group barriers; k-pipelines run independently.
//  P0: block-local adj mask -> LDS (64x redundant, ~7us, L2-fed; buys zero
//      grid syncs) + gat1 proj of own stripe -> HB1 chunk + f21 (sc1), f1s LDS
//  P1: attn layer 1 (FUSE)  -> HB2 + f22 (sc1), f1s (LDS)
//  P2: attn layer 2 + fused fc1 partials -> yp slots (sc1)
//  P3: blocks s<2: reduce yp + bias + relu -> out GEMV half
// ---------------------------------------------------------------------------
__global__ __launch_bounds__(512, 4) void mega_kernel(
        const int* __restrict__ adj,
        const float* __restrict__ X, const float* __restrict__ W1,
        const float* __restrict__ a1,
        uint4* __restrict__ HB1, float* __restrict__ f21,
        const float* __restrict__ W2, const float* __restrict__ a2,
        const float* __restrict__ fc1w,
        uint4* __restrict__ HB2, float* __restrict__ f22,
        float* __restrict__ yp,
        const float* __restrict__ fc1b, const float* __restrict__ outw,
        const float* __restrict__ outb, float* __restrict__ out) {
    __shared__ SharedBufs S;
    const int tid  = threadIdx.x;
    const int lane = tid & 63;
    const int wv   = tid >> 6;
    const int bid  = blockIdx.x;
    const int k    = bid >> 3;
    const int s    = bid & 7;

    // ---- P0a: adjacency mask for OWN 128 query rows -> LDS ----
    {
        const int r0 = s << 7;
        #pragma unroll 8
        for (int u = 0; u < 256; u++) {              // wave: 16 rows x 16 jw
            const int lr = (wv << 4) + (u >> 4);
            const int jw = u & 15;
            int v = adj[(r0 + lr) * N + (jw << 6) + lane];  // coalesced 256B
            ull m = __ballot(v > 0);                 // bit lane = adj>0
            if (lane == 0) S.mask[lr * 18 + jw] = m;
        }
    }

    // ---- P0b: gat1 proj of own 128-row stripe of k ----
    {
        const int j0 = s << 7;
        if (tid < 128) {
            const int idx = k * N + j0 + tid;
            const float4* x4 = (const float4*)(X + (size_t)idx * DIN);
            float hv_[H1] = {0.f, 0.f, 0.f, 0.f};
            #pragma unroll
            for (int q = 0; q < 4; q++) {
                float4 xv = x4[q];
                #pragma unroll
                for (int f = 0; f < H1; f++) {
                    hv_[f] += xv.x * W1[(q * 4 + 0) * H1 + f] + xv.y * W1[(q * 4 + 1) * H1 + f]
                            + xv.z * W1[(q * 4 + 2) * H1 + f] + xv.w * W1[(q * 4 + 3) * H1 + f];
                }
            }
            float s1 = 0.f, s2 = 0.f;
            #pragma unroll
            for (int f = 0; f < H1; f++) { s1 += hv_[f] * a1[f]; s2 += hv_[f] * a1[H1 + f]; }
            S.f1s[tid] = s1 * LOG2E_F;               // own-row: LDS only
            store_dev(&f21[idx], s2 * LOG2E_F);      // group-wide: sc1
            #pragma unroll
            for (int f = 0; f < H1; f++) S.hrow[tid * 4 + f] = hv_[f];
        }
        __syncthreads();
        if (tid < 256) {                             // 4 chunk-locals x 64 lanes
            int cl = tid >> 6, l = tid & 63, q = (l >> 4), n = l & 15;
            uint4 dw;
            if (n < H1) {
                const float* hp = S.hrow + (cl * 32 + q * 8) * 4 + n;
                dw.x = pk_bf16(hp[0],  hp[4]);
                dw.y = pk_bf16(hp[8],  hp[12]);
                dw.z = pk_bf16(hp[16], hp[20]);
                dw.w = pk_bf16(hp[24], hp[28]);
            } else if (n == H1) {
                dw = make_uint4(0x3f803f80u, 0x3f803f80u, 0x3f803f80u, 0x3f803f80u);
            } else {
                dw = make_uint4(0u, 0u, 0u, 0u);
            }
            ull* p = (ull*)&HB1[(size_t)k * 2048 + ((j0 >> 5) + cl) * 64 + l];
            store_dev64(p,     (ull)dw.x | ((ull)dw.y << 32));
            store_dev64(p + 1, (ull)dw.z | ((ull)dw.w << 32));
        }
    }

    group_barrier(0, k, true);

    // ---- P1: attention layer 1 (FUSE) ----
    attn_phase<H1, true>(HB1, f21, W2, a2, nullptr,
                         HB2, nullptr, f22, S, k, s);

    group_barrier(1, k, true);

    // ---- P2: attention layer 2 + fused fc1 partials ----
    attn_phase<DOUT, false>(HB2, f22, nullptr, nullptr, fc1w,
                            nullptr, yp, nullptr, S, k, s);

    group_barrier(2, k, s < 2);   // all arrive; only fc2 blocks wait

    // ---- P3: fc2 on blocks s<2 (n-half = s) ----
    if (s < 2) {
        if (tid < FC1) {
            float sum = fc1b[tid];
            #pragma unroll
            for (int sl = 0; sl < 8; sl++) sum += yp[((k << 3) + sl) * 64 + tid];
            S.ybuf[tid] = fmaxf(sum, 0.f);           // bias + relu
        }
        __syncthreads();
        const int n = (s << 9) + tid;                // 0..1023
        float sm = outb[n];
        #pragma unroll 6
        for (int cc = 0; cc < FC1; cc++)
            sm += S.ybuf[cc] * outw[(size_t)cc * N + n];
        out[(size_t)k * N + n] = sm;
    }
}

// ---------------------------------------------------------------------------
extern "C" void kernel_launch(void* const* d_in, const int* in_sizes, int n_in,
                              void* d_out, int out_size, void* d_ws, size_t ws_size,
                              hipStream_t stream) {
    const float* X     = (const float*)d_in[0];
    const int*   adj   = (const int*)  d_in[1];
    const float* W1    = (const float*)d_in[2];
    const float* a1    = (const float*)d_in[3];
    const float* W2    = (const float*)d_in[4];
    const float* a2    = (const float*)d_in[5];
    const float* fc1w  = (const float*)d_in[6];
    const float* fc1b  = (const float*)d_in[7];
    const float* outw  = (const float*)d_in[8];
    const float* outb  = (const float*)d_in[9];
    float* out = (float*)d_out;

    // Workspace layout (floats); ~4.6 MB total
    float* ws  = (float*)d_ws;
    float* f21 = ws;                       // 65536
    float* f22 = f21 + 65536;              // 65536
    float* yp  = f22 + 65536;              // 32768 (512 slots x 64)
    uint4* HB1 = (uint4*)(yp + 32768);     // 131072 u4
    uint4* HB2 = HB1 + 131072;             // 131072 u4

    mega_kernel<<<dim3(512), dim3(512), 0, stream>>>(
        adj, X, W1, a1, HB1, f21, W2, a2, fc1w,
        HB2, f22, yp, fc1b, outw, outb, out);
}

// Round 8
// 126.600 us; speedup vs baseline: 1.4610x; 1.4610x over previous
//
#include <hip/hip_runtime.h>
#include <hip/hip_bf16.h>

// Problem constants (from reference setup_inputs)
constexpr int K    = 64;
constexpr int N    = 1024;
constexpr int DIN  = 16;
constexpr int H1   = 4;
constexpr int DOUT = 8;
constexpr int FC1  = 54;

#define ALPHA_F   (0.01f)
#define LOG2E_F   (1.4426950408889634f)

typedef unsigned int uint;
typedef short  bf16x8 __attribute__((ext_vector_type(8)));
typedef float  f32x4  __attribute__((ext_vector_type(4)));

__device__ inline float fast_exp2(float x) {
#if __has_builtin(__builtin_amdgcn_exp2f)
    return __builtin_amdgcn_exp2f(x);      // raw v_exp_f32
#else
    return __expf(x * 0.6931471805599453f);
#endif
}

// packed bf16 pair (RNE) -> uint (lo=a, hi=b); v_cvt_pk_bf16_f32 on gfx950
__device__ inline uint pk_bf16(float a, float b) {
    union { __hip_bfloat162 h; uint u; } v;
    v.h = __float22bfloat162_rn(make_float2(a, b));
    return v.u;
}

// ---------------------------------------------------------------------------
// B-fragment table layout (consumed by mfma_f32_16x16x32_bf16):
//   HB[k][c][lane] : uint4;  lane=(q=lane>>4, n=lane&15)
//   dword t packs rows j=c*32+q*8+2t, +2t+1 of column n:
//   n<F -> bf16(h[j][n]); n==F -> 1.0 (denominator column); n>F -> 0.
// ---------------------------------------------------------------------------

// ---------------------------------------------------------------------------
// prep kernel (R2-verified): two jobs split by blockIdx range.
//  A) blocks [0,512):    maskM pack: each wave handles 4 (i,jw) units
//  B) blocks [512,640):  gat1 proj h=X@W1 -> f11/f21 logits (*log2e) AND
//                        HB1 bf16 B-fragment table (via LDS row-stage)
// ---------------------------------------------------------------------------
__global__ __launch_bounds__(512) void prep_kernel(
        const int* __restrict__ adj, unsigned long long* __restrict__ maskM,
        const float* __restrict__ X, const float* __restrict__ W1,
        const float* __restrict__ a1,
        uint4* __restrict__ HB1, float* __restrict__ f11, float* __restrict__ f21) {
    int b = blockIdx.x;
    if (b < 512) {
        int wv = threadIdx.x >> 6, lane = threadIdx.x & 63;
        int g = b * 8 + wv;                // 0..4095
        #pragma unroll
        for (int uu = 0; uu < 4; uu++) {
            int u = g * 4 + uu;            // 0..16383
            int jw = u >> 10;              // 0..15
            int i  = u & 1023;
            int v = adj[i * N + (jw << 6) + lane];    // coalesced 256B/wave
            unsigned long long m = __ballot(v > 0);   // bit lane = adj>0
            if (lane == 0) maskM[i * 16 + jw] = m;    // row-major
        }
    } else {
        __shared__ float hrow[512 * 4];               // 8 KB row-stage
        const int bb  = b - 512;                      // 0..127
        const int k   = bb >> 1;
        const int j0  = (bb & 1) * 512;
        const int tid = threadIdx.x;
        const int idx = k * N + j0 + tid;             // this thread's (k,j)
        const float4* x4 = (const float4*)(X + (size_t)idx * DIN);
        float hv_[H1] = {0.f, 0.f, 0.f, 0.f};
        #pragma unroll
        for (int q = 0; q < 4; q++) {
            float4 xv = x4[q];
            #pragma unroll
            for (int f = 0; f < H1; f++) {
                hv_[f] += xv.x * W1[(q * 4 + 0) * H1 + f] + xv.y * W1[(q * 4 + 1) * H1 + f]
                        + xv.z * W1[(q * 4 + 2) * H1 + f] + xv.w * W1[(q * 4 + 3) * H1 + f];
            }
        }
        float s1 = 0.f, s2 = 0.f;
        #pragma unroll
        for (int f = 0; f < H1; f++) { s1 += hv_[f] * a1[f]; s2 += hv_[f] * a1[H1 + f]; }
        f11[idx] = s1 * LOG2E_F;
        f21[idx] = s2 * LOG2E_F;
        #pragma unroll
        for (int f = 0; f < H1; f++) hrow[tid * 4 + f] = hv_[f];
        __syncthreads();
        // frag writes: local chunks cl=0..15 -> global chunks j0/32+cl
        uint4* HBk = HB1 + (size_t)k * 2048 + (j0 >> 5) * 64;
        #pragma unroll
        for (int e = tid; e < 1024; e += 512) {
            int cl = e >> 6, l = e & 63, q = (l >> 4), n = l & 15;
            uint4 dw;
            if (n < H1) {
                const float* hp = hrow + (cl * 32 + q * 8) * 4 + n;
                dw.x = pk_bf16(hp[0],  hp[4]);
                dw.y = pk_bf16(hp[8],  hp[12]);
                dw.z = pk_bf16(hp[16], hp[20]);
                dw.w = pk_bf16(hp[24], hp[28]);
            } else if (n == H1) {
                dw = make_uint4(0x3f803f80u, 0x3f803f80u, 0x3f803f80u, 0x3f803f80u);
            } else {
                dw = make_uint4(0u, 0u, 0u, 0u);
            }
            HBk[cl * 64 + l] = dw;
        }
    }
}

// ---------------------------------------------------------------------------
// MFMA attention v4: OCCUPANCY DOUBLED.  R6/R7 counters showed the attn
// phases are latency-stalled (VALUBusy ~30%, MFMA 1.3%, HBM 3%) at 16
// waves/CU — the limiter was GRID SIZE (512 blocks = 2/CU), not registers
// (VGPR 56 <= 64).  v4: grid K*16 = 1024 blocks, __launch_bounds__(512,8)
// -> 4 blocks/CU = 32 waves/CU (100%).  Each block owns 4 i-tiles; its 8
// waves = 4 i-tiles x 2 j-halves (16 chunks each).  Pair accumulators
// combine via LDS; epilogues run on even waves (fc1 partial split across
// the pair).  Main-loop chunk body is instruction-identical to R2.
// ---------------------------------------------------------------------------
template <int F, bool FUSE>
__global__ __launch_bounds__(512, 8) void gat_attn_mfma(
        const unsigned long long* __restrict__ maskM,  // [N][16] row-major
        const uint4* __restrict__ HBin,  // [K][32][64] B-frags
        const float* __restrict__ f1,    // [K,N]  (x log2e)
        const float* __restrict__ f2,    // [K,N]  (x log2e)
        const float* __restrict__ W2,    // [4,8]  (FUSE only)
        const float* __restrict__ a2,    // [16]   (FUSE only)
        const float* __restrict__ fc1w,  // [8192,54] (!FUSE only)
        uint4* __restrict__ HBout,       // FUSE: HB2 table
        float* __restrict__ yp,          // !FUSE: fc1 partial slots [1024][64]
        float* __restrict__ o_f1,        // FUSE: f12 (x log2e)
        float* __restrict__ o_f2) {      // FUSE: f22 (x log2e)
    __shared__ float F2s[1024];          // f2[k] (4 KB)
    __shared__ float ACC[4][64][4];      // pair-combine buffer (4 KB)
    __shared__ float XPa[4][16][5];      // FUSE: attn output xo
    __shared__ float XPb[4][16][9];      // FUSE: projected hv / !FUSE: xo tile
    __shared__ float YPs[8][64];         // !FUSE: per-wave fc1 partials

    const int tid  = threadIdx.x;
    const int lane = tid & 63;
    const int w    = tid >> 6;           // 0..7
    const int wv   = w >> 1;             // pair id 0..3 (i-tile local)
    const int half = w & 1;              // j-half
    const int quad = lane >> 4;
    const int n16  = lane & 15;
    const int k    = blockIdx.x >> 4;
    const int s4   = blockIdx.x & 15;

    if (tid < 256)
        ((float4*)F2s)[tid] = ((const float4*)(f2 + k * N))[tid];
    __syncthreads();

    const int itile = s4 * 4 + wv;                   // 0..63
    const int ibase = itile * 16;
    const int irow  = ibase + n16;                   // this lane's P row
    const float f1v = f1[k * N + irow];
    const uint4* mrow = (const uint4*)((const char*)maskM + (size_t)irow * 128);
    const uint4* HBk  = HBin + (size_t)k * 2048;

    f32x4 acc = {0.f, 0.f, 0.f, 0.f};
    union { bf16x8 v; uint u[4]; } af;
    union { bf16x8 v; uint4 q; }  bfrag;

    #pragma unroll 2
    for (int gg = 0; gg < 4; gg++) {
        const int g = half * 4 + gg;                 // this wave's j-half
        const uint4 Mg = mrow[g];                    // 4 chunks of mask bits
        #pragma unroll
        for (int cc = 0; cc < 4; cc++) {
            const int c = g * 4 + cc;
            const uint mdw = (cc == 0) ? Mg.x : (cc == 1) ? Mg.y
                           : (cc == 2) ? Mg.z : Mg.w;
            const uint mb  = (mdw >> (quad * 8)) & 0xffu;  // 8 bits, this lane
            float4 fa = *(const float4*)(F2s + c * 32 + quad * 8);
            float4 fb = *(const float4*)(F2s + c * 32 + quad * 8 + 4);
            bfrag.q = HBk[c * 64 + lane];            // coalesced VMEM (L2)
            float f2e[8] = {fa.x, fa.y, fa.z, fa.w, fb.x, fb.y, fb.z, fb.w};
            float pv[8];
            #pragma unroll
            for (int jj = 0; jj < 8; jj++) {
                float x = f1v + f2e[jj];
                float e = fmaxf(x, ALPHA_F * x);     // leaky (log2-scaled)
                float p = fast_exp2(e);
                pv[jj] = (mb & (1u << jj)) ? p : 0.f;  // mask -> exact 0
            }
            #pragma unroll
            for (int pr = 0; pr < 4; pr++)
                af.u[pr] = pk_bf16(pv[2 * pr], pv[2 * pr + 1]);
            acc = __builtin_amdgcn_mfma_f32_16x16x32_bf16(af.v, bfrag.v, acc, 0, 0, 0);
        }
    }

    // ---- pair combine: odd wave's partial acc += into even wave ----
    if (half) {
        #pragma unroll
        for (int r = 0; r < 4; r++) ACC[wv][lane][r] = acc[r];
    }
    __syncthreads();
    if (!half) {
        #pragma unroll
        for (int r = 0; r < 4; r++) acc[r] += ACC[wv][lane][r];
        // ---- epilogue: C[m][n]: n=lane&15, m=quad*4+reg; denom col n==F ----
        #pragma unroll
        for (int r = 0; r < 4; r++) {
            float den = __shfl(acc[r], (lane & 48) + F);
            float inv = (den > 0.f) ? 1.f / den : 0.f;
            float xo  = fmaxf(acc[r] * inv, 0.f);    // relu
            int m = quad * 4 + r;
            if constexpr (FUSE) {
                if (n16 < F) XPa[wv][m][n16] = xo;
            } else {
                if (n16 < F) XPb[wv][m][n16] = xo;   // stage for fc1
            }
        }
    }

    if constexpr (FUSE) {
        __syncthreads();
        if (!half && lane < 16) {
            const int m = lane;
            float x0 = XPa[wv][m][0], x1 = XPa[wv][m][1];
            float x2v = XPa[wv][m][2], x3 = XPa[wv][m][3];
            float hv[DOUT];
            #pragma unroll
            for (int f = 0; f < DOUT; f++) {
                hv[f] = x0 * W2[f]      + x1 * W2[8 + f]
                      + x2v * W2[16 + f] + x3 * W2[24 + f];
            }
            float t1 = 0.f, t2 = 0.f;
            #pragma unroll
            for (int f = 0; f < DOUT; f++) { t1 += hv[f] * a2[f]; t2 += hv[f] * a2[DOUT + f]; }
            const int row = k * N + ibase + m;
            o_f1[row] = t1 * LOG2E_F;
            o_f2[row] = t2 * LOG2E_F;
            #pragma unroll
            for (int f = 0; f < DOUT; f++) XPb[wv][m][f] = hv[f];
        }
        __syncthreads();
        if (!half && lane < 32) {
            const int c2    = ibase >> 5;
            const int qhalf = (ibase >> 4) & 1;
            const int ql    = lane >> 4;
            const int n     = lane & 15;
            const int q     = qhalf * 2 + ql;
            uint4 dw;
            if (n < DOUT) {
                dw.x = pk_bf16(XPb[wv][ql * 8 + 0][n], XPb[wv][ql * 8 + 1][n]);
                dw.y = pk_bf16(XPb[wv][ql * 8 + 2][n], XPb[wv][ql * 8 + 3][n]);
                dw.z = pk_bf16(XPb[wv][ql * 8 + 4][n], XPb[wv][ql * 8 + 5][n]);
                dw.w = pk_bf16(XPb[wv][ql * 8 + 6][n], XPb[wv][ql * 8 + 7][n]);
            } else if (n == DOUT) {
                dw = make_uint4(0x3f803f80u, 0x3f803f80u, 0x3f803f80u, 0x3f803f80u);
            } else {
                dw = make_uint4(0u, 0u, 0u, 0u);
            }
            HBout[(size_t)k * 2048 + c2 * 64 + q * 16 + n] = dw;
        }
    } else {
        // ---- fused fc1: pair splits the 128 x2-cols of its i-tile ----
        __syncthreads();                             // XPb visible to pair
        const int ceff = (lane < FC1) ? lane : 0;    // c = lane (54 active)
        const float* wb = fc1w + ((size_t)ibase * DOUT + half * 64) * FC1;
        float pacc = 0.f;
        #pragma unroll 8
        for (int mm = 0; mm < 64; mm++) {
            float xv = XPb[wv][half * 8 + (mm >> 3)][mm & 7];  // broadcast
            pacc = fmaf(xv, wb[(size_t)mm * FC1 + ceff], pacc);
        }
        YPs[w][lane] = pacc;
        __syncthreads();
        if (tid < 64) {
            float s = 0.f;
            #pragma unroll
            for (int ww = 0; ww < 8; ww++) s += YPs[ww][tid];
            yp[blockIdx.x * 64 + tid] = s;           // race-free slot write
        }
    }
}

// ---------------------------------------------------------------------------
// FC2 fused: reduce 16 fc1 partial slots + bias + relu -> ybuf[54] in LDS,
// then out[k,n] = ybuf . out_w[:,n] + out_b[n].
// Grid (2, K): blockIdx.x = n-half, blockIdx.y = k.  512 threads.
// ---------------------------------------------------------------------------
__global__ __launch_bounds__(512) void fc2_kernel(
        const float* __restrict__ yp, const float* __restrict__ fc1b,
        const float* __restrict__ outw, const float* __restrict__ outb,
        float* __restrict__ out) {
    __shared__ float ybuf[FC1];
    const int t = threadIdx.x;
    const int k = blockIdx.y;
    if (t < FC1) {
        float s = fc1b[t];
        #pragma unroll
        for (int sl = 0; sl < 16; sl++) s += yp[((k << 4) + sl) * 64 + t];
        ybuf[t] = fmaxf(s, 0.f);          // bias + relu
    }
    __syncthreads();
    const int n = blockIdx.x * 512 + t;   // 0..1023
    float s = outb[n];
    #pragma unroll 6
    for (int cc = 0; cc < FC1; cc++)
        s += ybuf[cc] * outw[(size_t)cc * N + n];
    out[(size_t)k * N + n] = s;
}

// ---------------------------------------------------------------------------
extern "C" void kernel_launch(void* const* d_in, const int* in_sizes, int n_in,
                              void* d_out, int out_size, void* d_ws, size_t ws_size,
                              hipStream_t stream) {
    const float* X     = (const float*)d_in[0];
    const int*   adj   = (const int*)  d_in[1];
    const float* W1    = (const float*)d_in[2];
    const float* a1    = (const float*)d_in[3];
    const float* W2    = (const float*)d_in[4];
    const float* a2    = (const float*)d_in[5];
    const float* fc1w  = (const float*)d_in[6];
    const float* fc1b  = (const float*)d_in[7];
    const float* outw  = (const float*)d_in[8];
    const float* outb  = (const float*)d_in[9];
    float* out = (float*)d_out;

    // Workspace layout (floats); ~5.5 MB total
    float* ws  = (float*)d_ws;
    float* f11 = ws;                       // 65536
    float* f21 = f11 + 65536;              // 65536
    float* f12 = f21 + 65536;              // 65536
    float* f22 = f12 + 65536;              // 65536
    float* yp  = f22 + 65536;              // 65536 (1024 slots x 64)
    unsigned long long* mM = (unsigned long long*)(yp + 65536);    // 16384 u64
    uint4* HB1 = (uint4*)(yp + 65536 + 32768);                     // 131072 u4
    uint4* HB2 = HB1 + 131072;                                     // 131072 u4

    // 1) prep: mask pack + gat1 proj -> HB1 frags + f11/f21
    prep_kernel<<<dim3(640), dim3(512), 0, stream>>>(
        adj, mM, X, W1, a1, HB1, f11, f21);

    // 2) layer-1 attention (FUSE) -> HB2 frags + f12/f22  [1024 blocks]
    gat_attn_mfma<H1, true><<<dim3(K * 16), dim3(512), 0, stream>>>(
        mM, HB1, f11, f21, W2, a2, nullptr, HB2, nullptr, f12, f22);

    // 3) layer-2 attention -> fused fc1 partial slots      [1024 blocks]
    gat_attn_mfma<DOUT, false><<<dim3(K * 16), dim3(512), 0, stream>>>(
        mM, HB2, f12, f22, nullptr, nullptr, fc1w, nullptr, yp, nullptr, nullptr);

    // 4) FC2: 16-slot reduce + bias + relu + output GEMV
    fc2_kernel<<<dim3(2, K), dim3(512), 0, stream>>>(yp, fc1b, outw, outb, out);
}